// Round 1
// baseline (2519.838 us; speedup 1.0000x reference)
//
#include <hip/hip_runtime.h>
#include <cfloat>

#define NROW   256      // B*E rows
#define RLEN   65536    // N*N elements per row
#define TPB    1024
#define EPT    64       // elements per thread (RLEN / TPB)
#define MAXC   12288    // candidate capacity (LDS)
#define NITER  64       // scan length (local_k)
#define KSEL   64       // top-k

// Zero the 64 MB output (float4 stores, coalesced). Runs before the main kernel.
__global__ void __launch_bounds__(TPB)
gumbel_zero_kernel(float4* __restrict__ out) {
    size_t i = (size_t)blockIdx.x * TPB + threadIdx.x;
    out[i] = make_float4(0.f, 0.f, 0.f, 0.f);
}

__global__ void __launch_bounds__(TPB)
GumbelSampler_2482491097709_kernel(const float* __restrict__ scores,
                                   const float* __restrict__ gumbel,
                                   float* __restrict__ out)
{
    __shared__ float s_red[16];
    __shared__ float s_mx[NITER];    // recorded 10*max(flat) per iteration
    __shared__ float s_rcp[NITER];   // recorded 1/sumexp
    __shared__ float s_t2[NITER];    // recorded log-mask activity threshold (y-space)
    __shared__ float s_lmin;         // min_t logsumexp_t  (x-space)
    __shared__ int   s_cnt;
    __shared__ int   s_selidx[KSEL];
    __shared__ float s_selval[KSEL];
    __shared__ float r_val[16];
    __shared__ int   r_idx[16];
    __shared__ int   r_slot[16];
    __shared__ float cand_val[MAXC]; // holds flat0, later overwritten with khot
    __shared__ int   cand_idx[MAXC];

    const int tid  = threadIdx.x;
    const int lane = tid & 63;
    const int wid  = tid >> 6;
    const int r    = blockIdx.x;   // row = b*4 + e
    const int b    = r >> 2;
    const int e    = r & 3;

    // flat0[p] = scores[b, i, j, e] + gumbel[r, p],  p = i*256 + j
    const float* __restrict__ srow = scores + (size_t)b * RLEN * 4 + e;
    const float* __restrict__ grow = gumbel + (size_t)r * RLEN;

    float f[EPT];
#pragma unroll
    for (int k = 0; k < EPT; ++k) {
        int p = tid + k * TPB;
        f[k] = srow[(size_t)p * 4] + grow[p];
    }

    if (tid == 0) s_lmin = FLT_MAX;
    __syncthreads();

    // ---- Pass 1: 64-iteration Gumbel-softmax scan; flat in registers ----
    for (int it = 0; it < NITER; ++it) {
        // Phase A: exact block max of flat (max is order-exact)
        float lm = f[0];
#pragma unroll
        for (int k = 1; k < EPT; ++k) lm = fmaxf(lm, f[k]);
#pragma unroll
        for (int o = 32; o > 0; o >>= 1) lm = fmaxf(lm, __shfl_down(lm, o));
        if (lane == 0) s_red[wid] = lm;
        __syncthreads();
        if (tid == 0) {
            float m = s_red[0];
            for (int w = 1; w < 16; ++w) m = fmaxf(m, s_red[w]);
            s_mx[it] = m * 10.0f;   // max in x = flat/TAU space (monotone-commutes)
        }
        __syncthreads();
        const float mx = s_mx[it];

        // Phase B: sumexp of exp((flat - max)/tau)
        float ls = 0.0f;
#pragma unroll
        for (int k = 0; k < EPT; ++k) {
            float y = fmaf(f[k], 10.0f, -mx);   // fmaf everywhere => bit-consistent
            ls += __expf(y);
        }
#pragma unroll
        for (int o = 32; o > 0; o >>= 1) ls += __shfl_down(ls, o);
        if (lane == 0) s_red[wid] = ls;
        __syncthreads();
        if (tid == 0) {
            float s = 0.0f;
            for (int w = 0; w < 16; ++w) s += s_red[w];
            float lnse = __logf(s);
            s_rcp[it] = 1.0f / s;
            // onehot > 2^-25 requires y > lnse - 17.328; margin 0.7 keeps skip exact
            s_t2[it]  = lnse - 18.03f;
            float L = s_mx[it] + lnse;          // logsumexp (x-space)
            if (L < s_lmin) s_lmin = L;
        }
        __syncthreads();

        // Phase C: flat += log(max(1-onehot, tiny)). Skipping lanes with
        // onehot <= ~1.5e-8 is EXACT: fl(1-o)=1 => log=0. Last iter's mask
        // never affects khot -> skipped (mirrored in the replay).
        if (it != NITER - 1) {
            const float rcp = s_rcp[it];
            const float t2  = s_t2[it];
#pragma unroll
            for (int k = 0; k < EPT; ++k) {
                float y = fmaf(f[k], 10.0f, -mx);
                bool act = (y > t2);
                if (__any(act)) {          // wave-level skip (~70% positions idle)
                    if (act) {
                        float o = __expf(y) * rcp;
                        f[k] += __logf(fmaxf(1.0f - o, FLT_MIN));
                    }
                }
            }
        }
    }
    __syncthreads();
    const float lmin = s_lmin;

    // ---- Candidate scan: khot_j <= 64*exp(x0_j - lmin); cutoff 64*e^-35 ~ 4e-14 ----
    // Reload flat0 into the (now dead) f[] registers.
#pragma unroll
    for (int k = 0; k < EPT; ++k) {
        int p = tid + k * TPB;
        f[k] = srow[(size_t)p * 4] + grow[p];
    }

    float cutoff = 35.0f;
    int cnt = 0;
    while (true) {
        if (tid == 0) s_cnt = 0;
        __syncthreads();
        const float thrF = (lmin - cutoff) * 0.1f;
#pragma unroll
        for (int k = 0; k < EPT; ++k) {
            if (f[k] >= thrF) {
                int slot = atomicAdd(&s_cnt, 1);
                if (slot < MAXC) {
                    cand_val[slot] = f[k];
                    cand_idx[slot] = tid + k * TPB;
                }
            }
        }
        __syncthreads();
        cnt = s_cnt;
        if (cnt <= MAXC || cutoff <= 6.0f) break;
        cutoff -= 10.0f;     // overflow fallback (statistically never taken)
        __syncthreads();     // all reads of s_cnt done before next reset
    }
    if (cnt > MAXC) cnt = MAXC;

    // ---- Pass 2: replay the identical arithmetic per candidate -> exact khot ----
    for (int s2 = tid; s2 < cnt; s2 += TPB) {
        float ff = cand_val[s2];
        float kh = 0.0f;
        for (int t = 0; t < NITER; ++t) {
            float y = fmaf(ff, 10.0f, -s_mx[t]);
            float o = __expf(y) * s_rcp[t];
            kh += o;                                  // same t-order as reference scan
            if (t != NITER - 1 && y > s_t2[t]) {
                ff += __logf(fmaxf(1.0f - o, FLT_MIN));
            }
        }
        cand_val[s2] = kh;
    }
    __syncthreads();

    // ---- Selection: 64 argmax rounds, jax top_k tie-break (val desc, idx asc) ----
    for (int round = 0; round < KSEL; ++round) {
        float bv = -1.0f; int bi = 0x7fffffff; int bs = -1;
        for (int s2 = tid; s2 < cnt; s2 += TPB) {
            float v = cand_val[s2];
            int   i = cand_idx[s2];
            if (v > bv || (v == bv && i < bi)) { bv = v; bi = i; bs = s2; }
        }
#pragma unroll
        for (int o = 32; o > 0; o >>= 1) {
            float ov = __shfl_down(bv, o);
            int   oi = __shfl_down(bi, o);
            int   os = __shfl_down(bs, o);
            if (ov > bv || (ov == bv && oi < bi)) { bv = ov; bi = oi; bs = os; }
        }
        if (lane == 0) { r_val[wid] = bv; r_idx[wid] = bi; r_slot[wid] = bs; }
        __syncthreads();
        if (tid == 0) {
            float Bv = r_val[0]; int Bi = r_idx[0]; int Bs = r_slot[0];
            for (int w = 1; w < 16; ++w) {
                if (r_val[w] > Bv || (r_val[w] == Bv && r_idx[w] < Bi)) {
                    Bv = r_val[w]; Bi = r_idx[w]; Bs = r_slot[w];
                }
            }
            s_selidx[round] = Bi;
            s_selval[round] = Bv;
            if (Bs >= 0) cand_val[Bs] = -1.0f;   // remove selected
        }
        __syncthreads();
    }

    // ---- Scatter: out[b,i,j,e] = (1 - khot) + khot at selected; 0 elsewhere ----
    if (tid < KSEL) {
        float kv = s_selval[tid];
        if (kv >= 0.0f) {
            int p = s_selidx[tid];
            out[((size_t)b * RLEN + (size_t)p) * 4 + e] = (1.0f - kv) + kv;
        }
    }
}

extern "C" void kernel_launch(void* const* d_in, const int* in_sizes, int n_in,
                              void* d_out, int out_size, void* d_ws, size_t ws_size,
                              hipStream_t stream) {
    const float* scores = (const float*)d_in[0];   // [B=64, N=256, N=256, E=4] f32
    const float* gumbel = (const float*)d_in[1];   // [B*E=256, N*N=65536] f32
    float* out = (float*)d_out;                    // [B, N, N, E] f32

    // out_size = 16,777,216 floats = 4,194,304 float4
    int nvec4 = out_size / 4;
    int zgrid = (nvec4 + TPB - 1) / TPB;
    gumbel_zero_kernel<<<zgrid, TPB, 0, stream>>>((float4*)out);
    GumbelSampler_2482491097709_kernel<<<NROW, TPB, 0, stream>>>(scores, gumbel, out);
}

// Round 2
// 1266.939 us; speedup vs baseline: 1.9889x; 1.9889x over previous
//
#include <hip/hip_runtime.h>
#include <cfloat>

#define NROW   256      // B*E rows
#define RLEN   65536    // N*N elements per row
#define TPB    1024
#define EPT    64       // elements per thread (RLEN / TPB)
#define MAXC   12288    // candidate capacity (LDS)
#define NITER  64       // scan length (local_k)
#define KSEL   64       // top-k

// Zero the 64 MB output (float4 stores, coalesced). Runs before the main kernel.
__global__ void __launch_bounds__(TPB)
gumbel_zero_kernel(float4* __restrict__ out) {
    size_t i = (size_t)blockIdx.x * TPB + threadIdx.x;
    out[i] = make_float4(0.f, 0.f, 0.f, 0.f);
}

// __launch_bounds__(1024, 4): 16 waves/block = 4 waves/SIMD => 128-VGPR budget.
// Without the ",4" the compiler targets 64 VGPRs (8 waves/SIMD) and spills the
// entire f[64] flat array to scratch (measured: 7 GB spill traffic, 2.5 ms).
// LDS (100 KB) limits us to 1 block/CU anyway, so 4 waves/SIMD costs nothing.
__global__ void __launch_bounds__(TPB, 4)
GumbelSampler_2482491097709_kernel(const float* __restrict__ scores,
                                   const float* __restrict__ gumbel,
                                   float* __restrict__ out)
{
    __shared__ float s_red[16];
    __shared__ float s_mx[NITER];    // recorded 10*max(flat) per iteration
    __shared__ float s_rcp[NITER];   // recorded 1/sumexp
    __shared__ float s_t2[NITER];    // recorded log-mask activity threshold (y-space)
    __shared__ float s_lmin;         // min_t logsumexp_t  (x-space)
    __shared__ int   s_cnt;
    __shared__ int   s_selidx[KSEL];
    __shared__ float s_selval[KSEL];
    __shared__ float r_val[16];
    __shared__ int   r_idx[16];
    __shared__ int   r_slot[16];
    __shared__ float cand_val[MAXC]; // holds flat0, later overwritten with khot
    __shared__ int   cand_idx[MAXC];

    const int tid  = threadIdx.x;
    const int lane = tid & 63;
    const int wid  = tid >> 6;
    const int r    = blockIdx.x;   // row = b*4 + e
    const int b    = r >> 2;
    const int e    = r & 3;

    // flat0[p] = scores[b, i, j, e] + gumbel[r, p],  p = i*256 + j
    const float* __restrict__ srow = scores + (size_t)b * RLEN * 4 + e;
    const float* __restrict__ grow = gumbel + (size_t)r * RLEN;

    float f[EPT];
#pragma unroll
    for (int k = 0; k < EPT; ++k) {
        int p = tid + k * TPB;
        f[k] = srow[(size_t)p * 4] + grow[p];
    }

    if (tid == 0) s_lmin = FLT_MAX;
    __syncthreads();

    // ---- Pass 1: 64-iteration Gumbel-softmax scan; flat entirely in registers.
    // Per iteration: (fused mask-update from prev iter + block max) then sumexp.
    // The per-element op sequence (fmaf/exp/log on recorded s_mx/s_rcp/s_t2) is
    // bit-identical to the candidate replay in Pass 2 -> exact khot recovery.
    for (int it = 0; it < NITER; ++it) {
        // Phase A: apply previous iteration's mask update, then local max.
        // Skipping lanes with onehot <= ~1.5e-8 is EXACT: fl(1-o)=1 => log1=0.
        float lm = -FLT_MAX;
        if (it > 0) {
            const float pmx  = s_mx[it - 1];
            const float prcp = s_rcp[it - 1];
            const float pt2  = s_t2[it - 1];
#pragma unroll
            for (int k = 0; k < EPT; ++k) {
                float y = fmaf(f[k], 10.0f, -pmx);
                bool act = (y > pt2);
                if (__any(act)) {          // wave-level skip (most positions idle)
                    if (act) {
                        float o = __expf(y) * prcp;
                        f[k] += __logf(fmaxf(1.0f - o, FLT_MIN));
                    }
                }
                lm = fmaxf(lm, f[k]);
            }
        } else {
#pragma unroll
            for (int k = 0; k < EPT; ++k) lm = fmaxf(lm, f[k]);
        }
#pragma unroll
        for (int o = 32; o > 0; o >>= 1) lm = fmaxf(lm, __shfl_down(lm, o));
        if (lane == 0) s_red[wid] = lm;
        __syncthreads();
        if (tid == 0) {
            float m = s_red[0];
            for (int w = 1; w < 16; ++w) m = fmaxf(m, s_red[w]);
            s_mx[it] = m * 10.0f;   // max in x = flat/TAU space (monotone-commutes)
        }
        __syncthreads();
        const float mx = s_mx[it];

        // Phase B: sumexp of exp((flat - max)/tau)
        float ls = 0.0f;
#pragma unroll
        for (int k = 0; k < EPT; ++k) {
            float y = fmaf(f[k], 10.0f, -mx);   // fmaf everywhere => bit-consistent
            ls += __expf(y);
        }
#pragma unroll
        for (int o = 32; o > 0; o >>= 1) ls += __shfl_down(ls, o);
        if (lane == 0) s_red[wid] = ls;
        __syncthreads();
        if (tid == 0) {
            float s = 0.0f;
            for (int w = 0; w < 16; ++w) s += s_red[w];
            float lnse = __logf(s);
            s_rcp[it] = 1.0f / s;
            // onehot > 2^-25 requires y > lnse - 17.328; margin 0.7 keeps skip exact
            s_t2[it]  = lnse - 18.03f;
            float L = s_mx[it] + lnse;          // logsumexp (x-space)
            if (L < s_lmin) s_lmin = L;
        }
        __syncthreads();
    }
    // NOTE: iteration NITER-1's mask update is intentionally never applied —
    // it cannot affect khot. Mirrored by the `t != NITER-1` guard in the replay.
    const float lmin = s_lmin;

    // ---- Candidate scan: khot_j <= 64*exp(x0_j - lmin); cutoff 64*e^-35 ~ 4e-14 ----
    // Reload flat0 into the (now dead) f[] registers (L3-warm by now).
#pragma unroll
    for (int k = 0; k < EPT; ++k) {
        int p = tid + k * TPB;
        f[k] = srow[(size_t)p * 4] + grow[p];
    }

    float cutoff = 35.0f;
    int cnt = 0;
    while (true) {
        if (tid == 0) s_cnt = 0;
        __syncthreads();
        const float thrF = (lmin - cutoff) * 0.1f;
#pragma unroll
        for (int k = 0; k < EPT; ++k) {
            if (f[k] >= thrF) {
                int slot = atomicAdd(&s_cnt, 1);
                if (slot < MAXC) {
                    cand_val[slot] = f[k];
                    cand_idx[slot] = tid + k * TPB;
                }
            }
        }
        __syncthreads();
        cnt = s_cnt;
        if (cnt <= MAXC || cutoff <= 6.0f) break;
        cutoff -= 10.0f;     // overflow fallback (statistically never taken)
        __syncthreads();     // all reads of s_cnt done before next reset
    }
    if (cnt > MAXC) cnt = MAXC;

    // ---- Pass 2: replay the identical arithmetic per candidate -> exact khot ----
    for (int s2 = tid; s2 < cnt; s2 += TPB) {
        float ff = cand_val[s2];
        float kh = 0.0f;
        for (int t = 0; t < NITER; ++t) {
            float y = fmaf(ff, 10.0f, -s_mx[t]);
            float o = __expf(y) * s_rcp[t];
            kh += o;                                  // same t-order as reference scan
            if (t != NITER - 1 && y > s_t2[t]) {
                ff += __logf(fmaxf(1.0f - o, FLT_MIN));
            }
        }
        cand_val[s2] = kh;
    }
    __syncthreads();

    // ---- Selection: 64 argmax rounds, jax top_k tie-break (val desc, idx asc) ----
    for (int round = 0; round < KSEL; ++round) {
        float bv = -1.0f; int bi = 0x7fffffff; int bs = -1;
        for (int s2 = tid; s2 < cnt; s2 += TPB) {
            float v = cand_val[s2];
            int   i = cand_idx[s2];
            if (v > bv || (v == bv && i < bi)) { bv = v; bi = i; bs = s2; }
        }
#pragma unroll
        for (int o = 32; o > 0; o >>= 1) {
            float ov = __shfl_down(bv, o);
            int   oi = __shfl_down(bi, o);
            int   os = __shfl_down(bs, o);
            if (ov > bv || (ov == bv && oi < bi)) { bv = ov; bi = oi; bs = os; }
        }
        if (lane == 0) { r_val[wid] = bv; r_idx[wid] = bi; r_slot[wid] = bs; }
        __syncthreads();
        if (tid == 0) {
            float Bv = r_val[0]; int Bi = r_idx[0]; int Bs = r_slot[0];
            for (int w = 1; w < 16; ++w) {
                if (r_val[w] > Bv || (r_val[w] == Bv && r_idx[w] < Bi)) {
                    Bv = r_val[w]; Bi = r_idx[w]; Bs = r_slot[w];
                }
            }
            s_selidx[round] = Bi;
            s_selval[round] = Bv;
            if (Bs >= 0) cand_val[Bs] = -1.0f;   // remove selected
        }
        __syncthreads();
    }

    // ---- Scatter: out[b,i,j,e] = (1 - khot) + khot at selected; 0 elsewhere ----
    if (tid < KSEL) {
        float kv = s_selval[tid];
        if (kv >= 0.0f) {
            int p = s_selidx[tid];
            out[((size_t)b * RLEN + (size_t)p) * 4 + e] = (1.0f - kv) + kv;
        }
    }
}

extern "C" void kernel_launch(void* const* d_in, const int* in_sizes, int n_in,
                              void* d_out, int out_size, void* d_ws, size_t ws_size,
                              hipStream_t stream) {
    const float* scores = (const float*)d_in[0];   // [B=64, N=256, N=256, E=4] f32
    const float* gumbel = (const float*)d_in[1];   // [B*E=256, N*N=65536] f32
    float* out = (float*)d_out;                    // [B, N, N, E] f32

    // out_size = 16,777,216 floats = 4,194,304 float4
    int nvec4 = out_size / 4;
    int zgrid = (nvec4 + TPB - 1) / TPB;
    gumbel_zero_kernel<<<zgrid, TPB, 0, stream>>>((float4*)out);
    GumbelSampler_2482491097709_kernel<<<NROW, TPB, 0, stream>>>(scores, gumbel, out);
}

// Round 3
// 1251.168 us; speedup vs baseline: 2.0140x; 1.0126x over previous
//
#include <hip/hip_runtime.h>
#include <cfloat>

#define NROW   256      // B*E rows
#define RLEN   65536    // N*N elements per row
#define TPB    1024
#define EPT    64       // elements per thread (RLEN / TPB)
#define MAXC   12288    // candidate capacity (LDS)
#define NITER  64       // scan length (local_k)
#define KSEL   64       // top-k

// Zero the 64 MB output (float4 stores, coalesced). Runs before the main kernel.
__global__ void __launch_bounds__(TPB)
gumbel_zero_kernel(float4* __restrict__ out) {
    size_t i = (size_t)blockIdx.x * TPB + threadIdx.x;
    out[i] = make_float4(0.f, 0.f, 0.f, 0.f);
}

// waves_per_eu(4,4): pin BOTH min and max occupancy to 4 waves/EU (= exactly
// the 1 block/CU that LDS=98KB and grid=256 already force). R1's
// __launch_bounds__(1024,4) set only the min — the allocator still chased
// 8 waves/EU (64-VGPR) occupancy and spilled f[64] (~670 MB scratch
// writebacks measured). Pinning max=4 gives the full 128-VGPR budget.
__global__ void __attribute__((amdgpu_flat_work_group_size(TPB, TPB),
                               amdgpu_waves_per_eu(4, 4)))
GumbelSampler_2482491097709_kernel(const float* __restrict__ scores,
                                   const float* __restrict__ gumbel,
                                   float* __restrict__ out)
{
    __shared__ float s_red[16];
    __shared__ float s_mx[NITER];    // recorded 10*max(flat) per iteration
    __shared__ float s_rcp[NITER];   // recorded 1/sumexp
    __shared__ float s_t2[NITER];    // recorded log-mask activity threshold (y-space)
    __shared__ float s_lmin;         // min_t logsumexp_t  (x-space)
    __shared__ int   s_cnt;
    __shared__ int   s_selidx[KSEL];
    __shared__ float s_selval[KSEL];
    __shared__ float r_val[16];
    __shared__ int   r_idx[16];
    __shared__ int   r_slot[16];
    __shared__ float cand_val[MAXC]; // holds flat0, later overwritten with khot
    __shared__ int   cand_idx[MAXC];

    const int tid  = threadIdx.x;
    const int lane = tid & 63;
    const int wid  = tid >> 6;

    // XCD-aware swizzle (perf heuristic only): blockIdx round-robins XCDs
    // (xcd = q % 8). Map so all 4 e-blocks of one b land on the SAME XCD:
    // its L2 then fetches scores[b]'s cachelines once instead of 4x.
    const int q    = blockIdx.x;
    const int xcd  = q & 7;
    const int slot = q >> 3;              // 0..31
    const int b    = xcd * 8 + (slot & 7);
    const int e    = slot >> 3;
    const int r    = b * 4 + e;           // row in gumbel

    // flat0[p] = scores[b, i, j, e] + gumbel[r, p],  p = i*256 + j
    const float* __restrict__ srow = scores + (size_t)b * RLEN * 4 + e;
    const float* __restrict__ grow = gumbel + (size_t)r * RLEN;

    float f[EPT];
#pragma unroll
    for (int k = 0; k < EPT; ++k) {
        int p = tid + k * TPB;
        f[k] = srow[(size_t)p * 4] + grow[p];
    }

    if (tid == 0) s_lmin = FLT_MAX;
    __syncthreads();

    // ---- Pass 1: 64-iteration Gumbel-softmax scan; flat entirely in registers.
    // Per iteration: (fused mask-update from prev iter + block max) then sumexp.
    // The per-element op sequence (fmaf/exp/log on recorded s_mx/s_rcp/s_t2) is
    // bit-identical to the candidate replay in Pass 2 -> exact khot recovery.
    for (int it = 0; it < NITER; ++it) {
        // Phase A: apply previous iteration's mask update, then local max.
        // Skipping lanes with onehot <= ~1.5e-8 is EXACT: fl(1-o)=1 => log1=0.
        float lm = -FLT_MAX;
        if (it > 0) {
            const float pmx  = s_mx[it - 1];
            const float prcp = s_rcp[it - 1];
            const float pt2  = s_t2[it - 1];
#pragma unroll
            for (int k = 0; k < EPT; ++k) {
                float y = fmaf(f[k], 10.0f, -pmx);
                bool act = (y > pt2);
                if (__any(act)) {          // wave-level skip (most positions idle)
                    if (act) {
                        float o = __expf(y) * prcp;
                        f[k] += __logf(fmaxf(1.0f - o, FLT_MIN));
                    }
                }
                lm = fmaxf(lm, f[k]);
            }
        } else {
#pragma unroll
            for (int k = 0; k < EPT; ++k) lm = fmaxf(lm, f[k]);
        }
#pragma unroll
        for (int o = 32; o > 0; o >>= 1) lm = fmaxf(lm, __shfl_down(lm, o));
        if (lane == 0) s_red[wid] = lm;
        __syncthreads();
        if (tid == 0) {
            float m = s_red[0];
            for (int w = 1; w < 16; ++w) m = fmaxf(m, s_red[w]);
            s_mx[it] = m * 10.0f;   // max in x = flat/TAU space (monotone-commutes)
        }
        __syncthreads();
        const float mx = s_mx[it];

        // Phase B: sumexp of exp((flat - max)/tau)
        float ls = 0.0f;
#pragma unroll
        for (int k = 0; k < EPT; ++k) {
            float y = fmaf(f[k], 10.0f, -mx);   // fmaf everywhere => bit-consistent
            ls += __expf(y);
        }
#pragma unroll
        for (int o = 32; o > 0; o >>= 1) ls += __shfl_down(ls, o);
        if (lane == 0) s_red[wid] = ls;
        __syncthreads();
        if (tid == 0) {
            float s = 0.0f;
            for (int w = 0; w < 16; ++w) s += s_red[w];
            float lnse = __logf(s);
            s_rcp[it] = 1.0f / s;
            // onehot > 2^-25 requires y > lnse - 17.328; margin 0.7 keeps skip exact
            s_t2[it]  = lnse - 18.03f;
            float L = s_mx[it] + lnse;          // logsumexp (x-space)
            if (L < s_lmin) s_lmin = L;
        }
        __syncthreads();
    }
    // NOTE: iteration NITER-1's mask update is intentionally never applied —
    // it cannot affect khot. Mirrored by the `t != NITER-1` guard in the replay.
    const float lmin = s_lmin;

    // ---- Candidate scan: khot_j <= 64*exp(x0_j - lmin); cutoff 64*e^-35 ~ 4e-14 ----
    // Reload flat0 into the (now dead) f[] registers (L3-warm by now).
#pragma unroll
    for (int k = 0; k < EPT; ++k) {
        int p = tid + k * TPB;
        f[k] = srow[(size_t)p * 4] + grow[p];
    }

    float cutoff = 35.0f;
    int cnt = 0;
    while (true) {
        if (tid == 0) s_cnt = 0;
        __syncthreads();
        const float thrF = (lmin - cutoff) * 0.1f;
#pragma unroll
        for (int k = 0; k < EPT; ++k) {
            if (f[k] >= thrF) {
                int slot2 = atomicAdd(&s_cnt, 1);
                if (slot2 < MAXC) {
                    cand_val[slot2] = f[k];
                    cand_idx[slot2] = tid + k * TPB;
                }
            }
        }
        __syncthreads();
        cnt = s_cnt;
        if (cnt <= MAXC || cutoff <= 6.0f) break;
        cutoff -= 10.0f;     // overflow fallback (statistically never taken)
        __syncthreads();     // all reads of s_cnt done before next reset
    }
    if (cnt > MAXC) cnt = MAXC;

    // ---- Pass 2: replay the identical arithmetic per candidate -> exact khot ----
    for (int s2 = tid; s2 < cnt; s2 += TPB) {
        float ff = cand_val[s2];
        float kh = 0.0f;
        for (int t = 0; t < NITER; ++t) {
            float y = fmaf(ff, 10.0f, -s_mx[t]);
            float o = __expf(y) * s_rcp[t];
            kh += o;                                  // same t-order as reference scan
            if (t != NITER - 1 && y > s_t2[t]) {
                ff += __logf(fmaxf(1.0f - o, FLT_MIN));
            }
        }
        cand_val[s2] = kh;
    }
    __syncthreads();

    // ---- Selection: 64 argmax rounds, jax top_k tie-break (val desc, idx asc) ----
    for (int round = 0; round < KSEL; ++round) {
        float bv = -1.0f; int bi = 0x7fffffff; int bs = -1;
        for (int s2 = tid; s2 < cnt; s2 += TPB) {
            float v = cand_val[s2];
            int   i = cand_idx[s2];
            if (v > bv || (v == bv && i < bi)) { bv = v; bi = i; bs = s2; }
        }
#pragma unroll
        for (int o = 32; o > 0; o >>= 1) {
            float ov = __shfl_down(bv, o);
            int   oi = __shfl_down(bi, o);
            int   os = __shfl_down(bs, o);
            if (ov > bv || (ov == bv && oi < bi)) { bv = ov; bi = oi; bs = os; }
        }
        if (lane == 0) { r_val[wid] = bv; r_idx[wid] = bi; r_slot[wid] = bs; }
        __syncthreads();
        if (tid == 0) {
            float Bv = r_val[0]; int Bi = r_idx[0]; int Bs = r_slot[0];
            for (int w = 1; w < 16; ++w) {
                if (r_val[w] > Bv || (r_val[w] == Bv && r_idx[w] < Bi)) {
                    Bv = r_val[w]; Bi = r_idx[w]; Bs = r_slot[w];
                }
            }
            s_selidx[round] = Bi;
            s_selval[round] = Bv;
            if (Bs >= 0) cand_val[Bs] = -1.0f;   // remove selected
        }
        __syncthreads();
    }

    // ---- Scatter: out[b,i,j,e] = (1 - khot) + khot at selected; 0 elsewhere ----
    if (tid < KSEL) {
        float kv = s_selval[tid];
        if (kv >= 0.0f) {
            int p = s_selidx[tid];
            out[((size_t)b * RLEN + (size_t)p) * 4 + e] = (1.0f - kv) + kv;
        }
    }
}

extern "C" void kernel_launch(void* const* d_in, const int* in_sizes, int n_in,
                              void* d_out, int out_size, void* d_ws, size_t ws_size,
                              hipStream_t stream) {
    const float* scores = (const float*)d_in[0];   // [B=64, N=256, N=256, E=4] f32
    const float* gumbel = (const float*)d_in[1];   // [B*E=256, N*N=65536] f32
    float* out = (float*)d_out;                    // [B, N, N, E] f32

    // out_size = 16,777,216 floats = 4,194,304 float4
    int nvec4 = out_size / 4;
    int zgrid = (nvec4 + TPB - 1) / TPB;
    gumbel_zero_kernel<<<zgrid, TPB, 0, stream>>>((float4*)out);
    GumbelSampler_2482491097709_kernel<<<NROW, TPB, 0, stream>>>(scores, gumbel, out);
}

// Round 4
// 642.279 us; speedup vs baseline: 3.9233x; 1.9480x over previous
//
#include <hip/hip_runtime.h>
#include <cfloat>

#define NROW   256      // B*E rows
#define RLEN   65536    // N*N elements per row
#define TPB    1024
#define EPT    64       // elements per thread (RLEN / TPB)
#define MAXC   6144     // candidate capacity (expected ~900-2200, 3-6x headroom)
#define NITER  64       // scan length (local_k)
#define KSEL   64       // top-k

// Zero the 64 MB output (float4 stores, coalesced). Runs before the main kernel.
__global__ void __launch_bounds__(TPB)
gumbel_zero_kernel(float4* __restrict__ out) {
    size_t i = (size_t)blockIdx.x * TPB + threadIdx.x;
    out[i] = make_float4(0.f, 0.f, 0.f, 0.f);
}

// SPARSE Gumbel-softmax scan. No per-thread flat[] array (R1-R3 spilled it:
// VGPR_Count pinned at 64 regardless of launch-bounds attributes; 756 MB/dispatch
// scratch writebacks). Only elements near the running max ever receive
// corrections; elements with onehot < 2^-25 have fl(1-o)=1 EXACTLY, so
// non-candidates are bit-frozen at flat0 and representable by aggregates:
//   mx_t = max(cand_max, Mu)           (Mu = exact max of non-candidates)
//   S_t  = cand_sum + U*exp(C - mx_t)  (U = exact sum of non-cand exps; share<=e^-18)
// Runtime trigger 10*Mu > Lse_t - 20 expands the candidate set mid-scan
// (exact: new members still bit-frozen; khot backfilled from recorded mx/rcp).
// Guaranteed to fire before a non-candidate becomes the max (lnse <= ln 65536 < 20).
// Top-64 of khot is always inside the candidate set: khot_noncand <= 64*e^-20
// = 1.3e-7 < khot_64th >= 1/S >= 1.5e-5.
__global__ void __launch_bounds__(TPB)
GumbelSampler_2482491097709_kernel(const float* __restrict__ scores,
                                   const float* __restrict__ gumbel,
                                   float* __restrict__ out)
{
    __shared__ float s_mx[NITER];    // recorded 10*max(flat) per iteration
    __shared__ float s_rcp[NITER];   // recorded 1/sumexp
    __shared__ float s_t2[NITER];    // recorded activity threshold (y-space)
    __shared__ float s_red[16];
    __shared__ float s_red2[16];
    __shared__ float s_scal[6];      // 0=M0 1=Mu 2=U 3=theta 4=lmin 5=Lse_cur
    __shared__ int   s_cnt, s_flag, s_noexp;
    __shared__ int   s_selidx[KSEL];
    __shared__ float s_selval[KSEL];
    __shared__ float r_val[16];
    __shared__ int   r_idx[16];
    __shared__ int   r_slot[16];
    __shared__ int   cand_idx[MAXC];
    __shared__ float cand_cur[MAXC]; // evolving flat value
    __shared__ float cand_kh[MAXC];  // accumulated khot

    const int tid  = threadIdx.x;
    const int lane = tid & 63;
    const int wid  = tid >> 6;

    // XCD swizzle: co-locate the 4 e-blocks of each b on one XCD so the
    // stride-16B scores lines are fetched once per XCD L2 (perf only).
    const int q    = blockIdx.x;
    const int xcd  = q & 7;
    const int slot = q >> 3;
    const int b    = xcd * 8 + (slot & 7);
    const int e    = slot >> 3;
    const int r    = b * 4 + e;

    const float* __restrict__ srow = scores + (size_t)b * RLEN * 4 + e;
    const float* __restrict__ grow = gumbel + (size_t)r * RLEN;

    // ---- Stream 1: block max M0 ----
    {
        float lm = -FLT_MAX;
        for (int k = 0; k < EPT; ++k) {
            int p = tid + k * TPB;
            lm = fmaxf(lm, srow[(size_t)p * 4] + grow[p]);
        }
#pragma unroll
        for (int o = 32; o > 0; o >>= 1) lm = fmaxf(lm, __shfl_down(lm, o));
        if (lane == 0) s_red[wid] = lm;
        __syncthreads();
        if (tid == 0) {
            float m = s_red[0];
#pragma unroll
            for (int w = 1; w < 16; ++w) m = fmaxf(m, s_red[w]);
            s_scal[0] = m;
            s_scal[4] = FLT_MAX;
            s_noexp   = 0;
        }
        __syncthreads();
    }
    const float C = s_scal[0] * 10.0f;   // exp anchor (x-space)

    // ---- Stream 2: initial candidate collect at theta = M0 - 6.5 (retry +1) ----
    float theta = s_scal[0] - 6.5f;
    int cnt;
    while (true) {
        if (tid == 0) s_cnt = 0;
        __syncthreads();
        float mu = -FLT_MAX, u = 0.f;
        for (int k = 0; k < EPT; ++k) {
            int p = tid + k * TPB;
            float v = srow[(size_t)p * 4] + grow[p];
            if (v >= theta) {
                int sl = atomicAdd(&s_cnt, 1);
                if (sl < MAXC) { cand_idx[sl] = p; cand_cur[sl] = v; cand_kh[sl] = 0.f; }
            } else {
                mu = fmaxf(mu, v);
                u += __expf(fmaf(v, 10.f, -C));
            }
        }
#pragma unroll
        for (int o = 32; o > 0; o >>= 1) {
            mu = fmaxf(mu, __shfl_down(mu, o));
            u += __shfl_down(u, o);
        }
        if (lane == 0) { s_red[wid] = mu; s_red2[wid] = u; }
        __syncthreads();
        if (tid == 0) {
            float M = -FLT_MAX, S = 0.f;
#pragma unroll
            for (int w = 0; w < 16; ++w) { M = fmaxf(M, s_red[w]); S += s_red2[w]; }
            s_scal[1] = M; s_scal[2] = S; s_scal[3] = theta;
        }
        __syncthreads();
        cnt = s_cnt;
        if (cnt <= MAXC) break;
        theta += 1.0f;
        __syncthreads();    // all threads done reading s_cnt before reset
    }

    // ---- Scan: 64 iterations over candidates only ----
    for (int t = 0; t < NITER; ++t) {
        // Phase A: replay-step for iteration t-1 (khot accumulate + correction),
        // then running max. Body is IDENTICAL to the per-element reference step.
        float lmx = -FLT_MAX;
        if (t > 0) {
            const float pmx = s_mx[t-1], prcp = s_rcp[t-1], pt2 = s_t2[t-1];
            for (int c = tid; c < cnt; c += TPB) {
                float cur = cand_cur[c];
                float y = fmaf(cur, 10.f, -pmx);
                float o = __expf(y) * prcp;
                cand_kh[c] += o;
                if (y > pt2) {      // o <= 1.5e-8 => fl(1-o)=1, skip is exact
                    cur += __logf(fmaxf(1.f - o, FLT_MIN));
                    cand_cur[c] = cur;
                }
                lmx = fmaxf(lmx, cur);
            }
        } else {
            for (int c = tid; c < cnt; c += TPB) lmx = fmaxf(lmx, cand_cur[c]);
        }
#pragma unroll
        for (int o = 32; o > 0; o >>= 1) lmx = fmaxf(lmx, __shfl_down(lmx, o));
        if (lane == 0) s_red[wid] = lmx;
        __syncthreads();
        if (tid == 0) {
            float m = s_red[0];
#pragma unroll
            for (int w = 1; w < 16; ++w) m = fmaxf(m, s_red[w]);
            m = fmaxf(m, s_scal[1]);          // true max includes untouched max
            s_mx[t] = m * 10.f;
        }
        __syncthreads();
        const float mx = s_mx[t];

        // Phase B: sumexp over candidates + untouched aggregate
        float ls = 0.f;
        for (int c = tid; c < cnt; c += TPB)
            ls += __expf(fmaf(cand_cur[c], 10.f, -mx));
#pragma unroll
        for (int o = 32; o > 0; o >>= 1) ls += __shfl_down(ls, o);
        if (lane == 0) s_red[wid] = ls;
        __syncthreads();
        if (tid == 0) {
            float S = 0.f;
#pragma unroll
            for (int w = 0; w < 16; ++w) S += s_red[w];
            float U = s_scal[2];
            // log-space to avoid exp(C-mx) overflow when the max is isolated
            if (U > 0.f) S += __expf(C - mx + __logf(U));
            float lnse = __logf(S);
            s_rcp[t] = 1.f / S;
            s_t2[t]  = lnse - 18.03f;
            float Lse = mx + lnse;
            if (Lse < s_scal[4]) s_scal[4] = Lse;
            s_scal[5] = Lse;
            // expansion trigger: guaranteed to fire before a non-candidate
            // could become active (lnse <= ln 65536 = 11.1 < 20)
            s_flag = (!s_noexp && t < NITER - 1 &&
                      10.f * s_scal[1] > Lse - 20.f) ? 1 : 0;
        }
        __syncthreads();

        if (s_flag) {
            // ---- exact mid-scan expansion: band [thN, thOld) joins ----
            const float thOld = s_scal[3];
            const float thN   = (s_scal[5] - 26.f) * 0.1f;
            const int   oldc  = cnt;
            float mu2 = -FLT_MAX;
            for (int k = 0; k < EPT; ++k) {
                int p = tid + k * TPB;
                float v = srow[(size_t)p * 4] + grow[p];
                if (v < thOld) {
                    if (v >= thN) {
                        int sl = atomicAdd(&s_cnt, 1);
                        if (sl < MAXC) {
                            cand_idx[sl] = p; cand_cur[sl] = v;
                            // khot backfill for iterations 0..t-1 (each < e^-20)
                            float kb = 0.f;
                            for (int tt = 0; tt < t; ++tt)
                                kb += __expf(fmaf(v, 10.f, -s_mx[tt])) * s_rcp[tt];
                            cand_kh[sl] = kb;
                        }
                    } else {
                        mu2 = fmaxf(mu2, v);
                    }
                }
            }
#pragma unroll
            for (int o = 32; o > 0; o >>= 1) mu2 = fmaxf(mu2, __shfl_down(mu2, o));
            if (lane == 0) s_red[wid] = mu2;
            __syncthreads();
            int newc = s_cnt;
            if (newc <= MAXC) {
                // commit: subtract appended band from U, update Mu/theta
                float du = 0.f;
                for (int c = oldc + tid; c < newc; c += TPB)
                    du += __expf(fmaf(cand_cur[c], 10.f, -C));
#pragma unroll
                for (int o = 32; o > 0; o >>= 1) du += __shfl_down(du, o);
                if (lane == 0) s_red2[wid] = du;
                __syncthreads();
                if (tid == 0) {
                    float M = -FLT_MAX, D = 0.f;
#pragma unroll
                    for (int w = 0; w < 16; ++w) { M = fmaxf(M, s_red[w]); D += s_red2[w]; }
                    s_scal[1] = M;
                    s_scal[2] = fmaxf(s_scal[2] - D, 0.f);  // guard tiny negative
                    s_scal[3] = thN;
                }
                __syncthreads();
                cnt = newc;
            } else {
                // capacity clamp (statistically never): discard, stop expanding
                __syncthreads();
                if (tid == 0) { s_cnt = oldc; s_noexp = 1; }
                __syncthreads();
                cnt = oldc;
            }
        }
    }

    // final iteration's onehot (t = NITER-1): accumulate, no correction
    {
        const float fmx = s_mx[NITER-1], frcp = s_rcp[NITER-1];
        for (int c = tid; c < cnt; c += TPB) {
            float y = fmaf(cand_cur[c], 10.f, -fmx);
            cand_kh[c] += __expf(y) * frcp;
        }
    }
    __syncthreads();

    // ---- Selection: 64 argmax rounds, jax top_k tie-break (val desc, idx asc) ----
    for (int round = 0; round < KSEL; ++round) {
        float bv = -1.0f; int bi = 0x7fffffff; int bs = -1;
        for (int c = tid; c < cnt; c += TPB) {
            float v = cand_kh[c];
            int   i = cand_idx[c];
            if (v > bv || (v == bv && i < bi)) { bv = v; bi = i; bs = c; }
        }
#pragma unroll
        for (int o = 32; o > 0; o >>= 1) {
            float ov = __shfl_down(bv, o);
            int   oi = __shfl_down(bi, o);
            int   os = __shfl_down(bs, o);
            if (ov > bv || (ov == bv && oi < bi)) { bv = ov; bi = oi; bs = os; }
        }
        if (lane == 0) { r_val[wid] = bv; r_idx[wid] = bi; r_slot[wid] = bs; }
        __syncthreads();
        if (tid == 0) {
            float Bv = r_val[0]; int Bi = r_idx[0]; int Bs = r_slot[0];
            for (int w = 1; w < 16; ++w) {
                if (r_val[w] > Bv || (r_val[w] == Bv && r_idx[w] < Bi)) {
                    Bv = r_val[w]; Bi = r_idx[w]; Bs = r_slot[w];
                }
            }
            s_selidx[round] = Bi;
            s_selval[round] = Bv;
            if (Bs >= 0) cand_kh[Bs] = -1.0f;   // remove selected
        }
        __syncthreads();
    }

    // ---- Scatter: out[b,i,j,e] = (1 - khot) + khot at selected; 0 elsewhere ----
    if (tid < KSEL) {
        float kv = s_selval[tid];
        if (kv >= 0.0f) {
            int p = s_selidx[tid];
            out[((size_t)b * RLEN + (size_t)p) * 4 + e] = (1.0f - kv) + kv;
        }
    }
}

extern "C" void kernel_launch(void* const* d_in, const int* in_sizes, int n_in,
                              void* d_out, int out_size, void* d_ws, size_t ws_size,
                              hipStream_t stream) {
    const float* scores = (const float*)d_in[0];   // [B=64, N=256, N=256, E=4] f32
    const float* gumbel = (const float*)d_in[1];   // [B*E=256, N*N=65536] f32
    float* out = (float*)d_out;                    // [B, N, N, E] f32

    int nvec4 = out_size / 4;
    int zgrid = (nvec4 + TPB - 1) / TPB;
    gumbel_zero_kernel<<<zgrid, TPB, 0, stream>>>((float4*)out);
    GumbelSampler_2482491097709_kernel<<<NROW, TPB, 0, stream>>>(scores, gumbel, out);
}